// Round 5
// baseline (310.998 us; speedup 1.0000x reference)
//
#include <hip/hip_runtime.h>
#include <cmath>

#define B_ 4
#define L_ 2048
#define S_ 2048
#define H_ 16
#define E_ 64
// 1/sqrt(64) * log2(e): exp2 (single v_exp_f32) instead of exp
#define SCALE2 0.18033688011112042f

typedef __attribute__((ext_vector_type(4))) float f32x4;
typedef __attribute__((ext_vector_type(8))) __bf16 bf16x8;
typedef __attribute__((ext_vector_type(8))) unsigned short ushort8;
union FragU { ushort8 u; bf16x8 b; };

__device__ __forceinline__ unsigned short f2bf(float f) {
    unsigned int u = __float_as_uint(f);
    return (unsigned short)((u + 0x7FFFu + ((u >> 16) & 1u)) >> 16);
}

__device__ __forceinline__ void gload_lds16(const void* g, void* l) {
    __builtin_amdgcn_global_load_lds(
        (const __attribute__((address_space(1))) void*)g,
        (__attribute__((address_space(3))) void*)l, 16, 0, 0);
}

// raw barrier / waitcnt: no vmcnt(0) drain (unlike __syncthreads)
#define ASM_BAR()  asm volatile("s_barrier" ::: "memory")
#define WAIT_V4()  asm volatile("s_waitcnt vmcnt(4)" ::: "memory")
#define WAIT_V0()  asm volatile("s_waitcnt vmcnt(0)" ::: "memory")

// ---- Prepass: K [b,s,h,e] fp32 -> Kbf [b,h,s,e] bf16, 16B chunks XOR-swizzled
// within each key row (dst chunk j holds src chunk j^(s&7)).
__global__ __launch_bounds__(256) void conv_k(const float* __restrict__ K,
                                              unsigned short* __restrict__ Kbf) {
    const int idx = blockIdx.x * 256 + threadIdx.x;
    const int j   = idx & 7;
    const int row = idx >> 3;            // (b*H+h)*S + s
    const int s   = row & (S_ - 1);
    const int bh  = row >> 11;
    const int h   = bh & (H_ - 1);
    const int b   = bh >> 4;
    const int jp  = j ^ (s & 7);
    const float* src = K + (((size_t)b * S_ + s) * H_ + h) * E_ + jp * 8;
    f32x4 a = *(const f32x4*)src;
    f32x4 d = *(const f32x4*)(src + 4);
    ushort8 u;
    u[0]=f2bf(a[0]); u[1]=f2bf(a[1]); u[2]=f2bf(a[2]); u[3]=f2bf(a[3]);
    u[4]=f2bf(d[0]); u[5]=f2bf(d[1]); u[6]=f2bf(d[2]); u[7]=f2bf(d[3]);
    *(ushort8*)(Kbf + (size_t)row * E_ + j * 8) = u;
}

// ---- Prepass: V [b,s,h,e] fp32 -> Vt [b,h,e,s] bf16 transposed, 16B chunks
// XOR-swizzled within each 64-s block (dst chunk lc holds src s-chunk lc^(e&7)).
__global__ __launch_bounds__(256) void conv_v(const float* __restrict__ V,
                                              unsigned short* __restrict__ Vt) {
    __shared__ unsigned short t[64 * 65];
    const int tid  = threadIdx.x;
    const int sblk = blockIdx.x & 31;
    const int h    = (blockIdx.x >> 5) & 15;
    const int b    = blockIdx.x >> 9;
    const int s0   = sblk * 64;
    for (int i = 0; i < 4; ++i) {
        const int c = tid + i * 256;
        const int sr = c >> 4, e0 = (c & 15) * 4;
        f32x4 a = *(const f32x4*)(V + (((size_t)b * S_ + s0 + sr) * H_ + h) * E_ + e0);
        t[sr * 65 + e0 + 0] = f2bf(a[0]);
        t[sr * 65 + e0 + 1] = f2bf(a[1]);
        t[sr * 65 + e0 + 2] = f2bf(a[2]);
        t[sr * 65 + e0 + 3] = f2bf(a[3]);
    }
    __syncthreads();
    for (int i = 0; i < 2; ++i) {
        const int c = tid + i * 256;
        const int e = c >> 3, lc = c & 7, sch = lc ^ (e & 7);
        ushort8 u;
        for (int k = 0; k < 8; ++k) u[k] = t[(sch * 8 + k) * 65 + e];
        *(ushort8*)(Vt + ((size_t)(b * H_ + h) * E_ + e) * S_ + s0 + lc * 8) = u;
    }
}

// ---- Main: 4 waves x 32 q-rows = 128 q-rows/block, causal flash attention,
// max-free softmax. Software-pipelined K-loop: double-buffered K+V LDS tiles
// via global_load_lds, raw s_barrier + s_waitcnt vmcnt(4) so the next tile's
// DMA stays in flight across this tile's compute (no vmcnt(0) barrier drain).
// In-loop VMEM = exactly 4 DMAs/wave/iter -> vmcnt bookkeeping is exact.
template <bool PRE>
__global__ __launch_bounds__(256, 4) void fattn_kernel(
    const float* __restrict__ Q, const unsigned short* __restrict__ Kbf,
    const unsigned short* __restrict__ Vt, const float* __restrict__ Kf,
    const float* __restrict__ Vf, float* __restrict__ Out)
{
    const int tid  = threadIdx.x;
    const int wave = tid >> 6;
    const int lane = tid & 63;
    const int ln   = lane & 15;
    const int quad = lane >> 4;
    const int qtile = gridDim.x - 1 - blockIdx.x;  // longest blocks first
    const int h = blockIdx.y;
    const int b = blockIdx.z;
    const int q0 = qtile * 128;
    const int qw = q0 + wave * 32;          // this wave's 32 q-rows
    const int p7 = ln & 7;

    __shared__ __align__(16) unsigned short ldsK[2][64 * 64];   // [key][e] swz
    __shared__ __align__(16) unsigned short ldsV[2][64 * 64];   // [e][s] swz
    __shared__ __align__(16) unsigned short ldsP[4][32 * 72];   // per-wave P

    // Q A-frags for both row-sets (m=ln, k=c*32+quad*8+j), pre-scaled.
    // Built BEFORE the first DMA so in-loop vmcnt counts only DMAs.
    FragU qf[2][2];
    for (int rs = 0; rs < 2; ++rs) {
        const float* qp = Q + (((size_t)b * L_ + (qw + rs * 16 + ln)) * H_ + h) * E_;
        for (int c = 0; c < 2; ++c) {
            const int e0 = c * 32 + quad * 8;
            f32x4 lo = *(const f32x4*)(qp + e0);
            f32x4 hi = *(const f32x4*)(qp + e0 + 4);
            ushort8 u;
            u[0]=f2bf(lo[0]*SCALE2); u[1]=f2bf(lo[1]*SCALE2);
            u[2]=f2bf(lo[2]*SCALE2); u[3]=f2bf(lo[3]*SCALE2);
            u[4]=f2bf(hi[0]*SCALE2); u[5]=f2bf(hi[1]*SCALE2);
            u[6]=f2bf(hi[2]*SCALE2); u[7]=f2bf(hi[3]*SCALE2);
            qf[rs][c].u = u;
        }
    }

    f32x4 o[2][4];
    for (int rs = 0; rs < 2; ++rs)
        for (int et = 0; et < 4; ++et) o[rs][et] = f32x4{0.f, 0.f, 0.f, 0.f};
    float l_r[2][4] = {{0.f,0.f,0.f,0.f},{0.f,0.f,0.f,0.f}};

    const unsigned short* kbh = Kbf + (size_t)(b * H_ + h) * S_ * E_;
    const unsigned short* vbh = Vt  + (size_t)(b * H_ + h) * E_ * S_;
    const float* kf32 = Kf + (((size_t)b * S_) * H_ + h) * E_;
    const float* vf32 = Vf + (((size_t)b * S_) * H_ + h) * E_;

    const int ntiles = 2 * qtile + 2;    // keys 0 .. q0+127

    if constexpr (PRE) {                 // prefetch tile 0 (4 DMAs/wave)
        for (int i = 0; i < 2; ++i) {
            const int slot0 = wave * 128 + i * 64;
            gload_lds16(kbh + (size_t)(slot0 + lane) * 8, &ldsK[0][slot0 * 8]);
        }
        for (int i = 0; i < 2; ++i) {
            const int slot0 = wave * 128 + i * 64;
            const int slot  = slot0 + lane;
            const int e = slot >> 3, lc = slot & 7;
            gload_lds16(vbh + (size_t)e * S_ + lc * 8, &ldsV[0][slot0 * 8]);
        }
    }

    for (int kt = 0; kt < ntiles; ++kt) {
        const int k0 = kt * 64;
        const unsigned short* kb;
        const unsigned short* vb;

        if constexpr (PRE) {
            if (kt + 1 < ntiles) {       // prefetch tile kt+1 into other buffer
                const int nb = (kt + 1) & 1;
                const unsigned short* ktb = kbh + (size_t)(k0 + 64) * E_;
                const unsigned short* vtb = vbh + (k0 + 64);
                for (int i = 0; i < 2; ++i) {
                    const int slot0 = wave * 128 + i * 64;
                    gload_lds16(ktb + (size_t)(slot0 + lane) * 8, &ldsK[nb][slot0 * 8]);
                }
                for (int i = 0; i < 2; ++i) {
                    const int slot0 = wave * 128 + i * 64;
                    const int slot  = slot0 + lane;
                    const int e = slot >> 3, lc = slot & 7;
                    gload_lds16(vtb + (size_t)e * S_ + lc * 8, &ldsV[nb][slot0 * 8]);
                }
                WAIT_V4();               // own tile-kt DMAs landed; kt+1 in flight
            } else {
                WAIT_V0();               // last tile: drain
            }
            ASM_BAR();                   // all waves' tile-kt DMAs landed
            kb = ldsK[kt & 1];
            vb = ldsV[kt & 1];
        } else {
            __syncthreads();
            for (int i = 0; i < 2; ++i) {          // fp32 fallback staging
                const int c = tid + i * 256;
                const int key = c >> 3, j = c & 7, jp = j ^ (key & 7);
                const float* src = kf32 + (size_t)(k0 + key) * (H_ * E_) + jp * 8;
                f32x4 a = *(const f32x4*)src, d = *(const f32x4*)(src + 4);
                ushort8 u;
                u[0]=f2bf(a[0]); u[1]=f2bf(a[1]); u[2]=f2bf(a[2]); u[3]=f2bf(a[3]);
                u[4]=f2bf(d[0]); u[5]=f2bf(d[1]); u[6]=f2bf(d[2]); u[7]=f2bf(d[3]);
                *(ushort8*)&ldsK[0][key * 64 + j * 8] = u;
            }
            for (int i = 0; i < 2; ++i) {
                const int c = tid + i * 256;
                const int e = c >> 3, lc = c & 7, sch = lc ^ (e & 7);
                ushort8 u;
                for (int t = 0; t < 8; ++t)
                    u[t] = f2bf(vf32[(size_t)(k0 + sch * 8 + t) * (H_ * E_) + e]);
                *(ushort8*)&ldsV[0][e * 64 + lc * 8] = u;
            }
            __syncthreads();
            kb = ldsK[0];
            vb = ldsV[0];
        }

        // wave-uniform causal classification (branch-around keeps barrier
        // counts uniform — no `continue` across barriers)
        if (k0 <= qw + 31) {
            const bool need_mask = (k0 + 63 > qw);  // diagonal tile

            // S = Q.K^T, both row-sets sharing K B-frags
            f32x4 sfr[2][4];
            for (int n = 0; n < 4; ++n) {
                FragU kf0, kf1;
                kf0.u = *(const ushort8*)&kb[(n*16+ln)*64 + ((quad    ) ^ p7) * 8];
                kf1.u = *(const ushort8*)&kb[(n*16+ln)*64 + ((4 + quad) ^ p7) * 8];
                for (int rs = 0; rs < 2; ++rs) {
                    f32x4 acc = f32x4{0.f, 0.f, 0.f, 0.f};
                    acc = __builtin_amdgcn_mfma_f32_16x16x32_bf16(qf[rs][0].b, kf0.b, acc, 0, 0, 0);
                    acc = __builtin_amdgcn_mfma_f32_16x16x32_bf16(qf[rs][1].b, kf1.b, acc, 0, 0, 0);
                    sfr[rs][n] = acc;
                }
            }

            // max-free softmax: p = 2^(s'); truncate to bf16; l accumulates
            // the truncated value so num/denom rounding cancels.
            for (int rs = 0; rs < 2; ++rs) {
                for (int r = 0; r < 4; ++r) {
                    const int qrow = qw + rs * 16 + quad * 4 + r;
                    for (int n = 0; n < 4; ++n) {
                        float p = __builtin_exp2f(sfr[rs][n][r]);
                        if (need_mask) {
                            const int col = k0 + n * 16 + ln;
                            p = (col <= qrow) ? p : 0.f;
                        }
                        const unsigned int u = __float_as_uint(p) & 0xFFFF0000u;
                        l_r[rs][r] += __uint_as_float(u);
                        ldsP[wave][(rs * 16 + quad * 4 + r) * 72 + n * 16 + ln] =
                            (unsigned short)(u >> 16);
                    }
                }
            }

            // O += P.V, V B-frags shared across row-sets
            FragU pf[2][2];
            for (int rs = 0; rs < 2; ++rs) {
                pf[rs][0].u = *(const ushort8*)&ldsP[wave][(rs*16+ln) * 72 + quad * 8];
                pf[rs][1].u = *(const ushort8*)&ldsP[wave][(rs*16+ln) * 72 + 32 + quad * 8];
            }
            for (int et = 0; et < 4; ++et) {
                FragU vf0, vf1;
                vf0.u = *(const ushort8*)&vb[(et*16+ln)*64 + ((quad    ) ^ p7) * 8];
                vf1.u = *(const ushort8*)&vb[(et*16+ln)*64 + ((4 + quad) ^ p7) * 8];
                for (int rs = 0; rs < 2; ++rs) {
                    o[rs][et] = __builtin_amdgcn_mfma_f32_16x16x32_bf16(pf[rs][0].b, vf0.b, o[rs][et], 0, 0, 0);
                    o[rs][et] = __builtin_amdgcn_mfma_f32_16x16x32_bf16(pf[rs][1].b, vf1.b, o[rs][et], 0, 0, 0);
                }
            }
        }

        if constexpr (PRE) {
            ASM_BAR();   // all reads of buf[kt&1] done before iter kt+1 reuses it
        }
    }

    // single end-of-kernel l reduction (16-lane groups) + store
    for (int rs = 0; rs < 2; ++rs) {
        for (int r = 0; r < 4; ++r) {
            float s = l_r[rs][r];
            s += __shfl_xor(s, 1); s += __shfl_xor(s, 2);
            s += __shfl_xor(s, 4); s += __shfl_xor(s, 8);
            const float inv = 1.f / s;
            const int qrow = qw + rs * 16 + quad * 4 + r;
            float* op = Out + (((size_t)b * L_ + qrow) * H_ + h) * E_;
            for (int et = 0; et < 4; ++et)
                op[et * 16 + ln] = o[rs][et][r] * inv;
        }
    }
}

extern "C" void kernel_launch(void* const* d_in, const int* in_sizes, int n_in,
                              void* d_out, int out_size, void* d_ws, size_t ws_size,
                              hipStream_t stream) {
    const float* Q = (const float*)d_in[0];
    const float* K = (const float*)d_in[1];
    const float* V = (const float*)d_in[2];
    // d_in[3] (causal mask) applied analytically in-kernel.
    float* Out = (float*)d_out;

    const size_t plane = (size_t)B_ * H_ * S_ * E_;
    unsigned short* Kbf = (unsigned short*)d_ws;
    unsigned short* Vt  = Kbf + plane;

    dim3 grid(L_ / 128, H_, B_);
    if (ws_size >= plane * 2 * sizeof(unsigned short)) {
        conv_k<<<(int)(plane / 8 / 256), 256, 0, stream>>>(K, Kbf);
        conv_v<<<B_ * H_ * (S_ / 64), 256, 0, stream>>>(V, Vt);
        fattn_kernel<true><<<grid, dim3(256), 0, stream>>>(Q, Kbf, Vt, K, V, Out);
    } else {
        fattn_kernel<false><<<grid, dim3(256), 0, stream>>>(Q, Kbf, Vt, K, V, Out);
    }
}

// Round 6
// 257.667 us; speedup vs baseline: 1.2070x; 1.2070x over previous
//
#include <hip/hip_runtime.h>
#include <cmath>

#define B_ 4
#define L_ 2048
#define S_ 2048
#define H_ 16
#define E_ 64
// 1/sqrt(64) * log2(e): exp2 (single v_exp_f32) instead of exp
#define SCALE2 0.18033688011112042f

typedef __attribute__((ext_vector_type(4))) float f32x4;
typedef __attribute__((ext_vector_type(8))) __bf16 bf16x8;
typedef __attribute__((ext_vector_type(8))) unsigned short ushort8;
union FragU { ushort8 u; bf16x8 b; unsigned int d[4]; };

__device__ __forceinline__ unsigned short f2bf(float f) {
    unsigned int u = __float_as_uint(f);
    return (unsigned short)((u + 0x7FFFu + ((u >> 16) & 1u)) >> 16);
}

// pack two fp32 (truncate) into one dword of 2 bf16: {hi[31:16], lo[31:16]}
__device__ __forceinline__ unsigned int pack_bf(float hi, float lo) {
    return __builtin_amdgcn_perm(__float_as_uint(hi), __float_as_uint(lo),
                                 0x07060302u);
}

__device__ __forceinline__ void gload_lds16(const void* g, void* l) {
    __builtin_amdgcn_global_load_lds(
        (const __attribute__((address_space(1))) void*)g,
        (__attribute__((address_space(3))) void*)l, 16, 0, 0);
}

// ---- Prepass: K [b,s,h,e] fp32 -> Kbf [b,h,s,e] bf16, 16B chunks XOR-swizzled
// within each key row (dst chunk j holds src chunk j^(s&7)).
__global__ __launch_bounds__(256) void conv_k(const float* __restrict__ K,
                                              unsigned short* __restrict__ Kbf) {
    const int idx = blockIdx.x * 256 + threadIdx.x;
    const int j   = idx & 7;
    const int row = idx >> 3;            // (b*H+h)*S + s
    const int s   = row & (S_ - 1);
    const int bh  = row >> 11;
    const int h   = bh & (H_ - 1);
    const int b   = bh >> 4;
    const int jp  = j ^ (s & 7);
    const float* src = K + (((size_t)b * S_ + s) * H_ + h) * E_ + jp * 8;
    f32x4 a = *(const f32x4*)src;
    f32x4 d = *(const f32x4*)(src + 4);
    ushort8 u;
    u[0]=f2bf(a[0]); u[1]=f2bf(a[1]); u[2]=f2bf(a[2]); u[3]=f2bf(a[3]);
    u[4]=f2bf(d[0]); u[5]=f2bf(d[1]); u[6]=f2bf(d[2]); u[7]=f2bf(d[3]);
    *(ushort8*)(Kbf + (size_t)row * E_ + j * 8) = u;
}

// ---- Prepass: V [b,s,h,e] fp32 -> Vt [b,h,e,s'] bf16, transposed per head,
// with the PERMUTED-K interleave baked in: within each 64-key block, stored
// chunk cc (= q*2+half) holds keys {(2*half+d)*16 + q*4 + r : d=0,1; r=0..3},
// then chunks XOR-swizzled by (e&7). This makes the main kernel's V B-frags
// (k = quad*8+j <-> key = (j>=4?n_hi:n_lo)*16+quad*4+(j&3)) plain b128 reads.
__global__ __launch_bounds__(256) void conv_v(const float* __restrict__ V,
                                              unsigned short* __restrict__ Vt) {
    __shared__ unsigned short t[64 * 65];
    const int tid  = threadIdx.x;
    const int sblk = blockIdx.x & 31;
    const int h    = (blockIdx.x >> 5) & 15;
    const int b    = blockIdx.x >> 9;
    const int s0   = sblk * 64;
    for (int i = 0; i < 4; ++i) {
        const int c = tid + i * 256;
        const int sr = c >> 4, e0 = (c & 15) * 4;
        f32x4 a = *(const f32x4*)(V + (((size_t)b * S_ + s0 + sr) * H_ + h) * E_ + e0);
        t[sr * 65 + e0 + 0] = f2bf(a[0]);
        t[sr * 65 + e0 + 1] = f2bf(a[1]);
        t[sr * 65 + e0 + 2] = f2bf(a[2]);
        t[sr * 65 + e0 + 3] = f2bf(a[3]);
    }
    __syncthreads();
    for (int i = 0; i < 2; ++i) {
        const int c  = tid + i * 256;
        const int e  = c >> 3, cc = c & 7;
        const int q  = cc >> 1, half = cc & 1;
        ushort8 u;
        for (int j = 0; j < 8; ++j) {
            const int d = j >> 2, r = j & 3;
            const int key = (2 * half + d) * 16 + q * 4 + r;
            u[j] = t[key * 65 + e];
        }
        *(ushort8*)(Vt + ((size_t)(b * H_ + h) * E_ + e) * S_ + s0
                    + (cc ^ (e & 7)) * 8) = u;
    }
}

// ---- Main: 4 waves x 16 q-rows = 64 q-rows/block (R2's proven shape).
// Causal flash attention, max-free softmax. Core computes S^T = K.Q^T so P
// stays in REGISTERS (C-layout == A-layout under a permuted-k bijection):
// no P LDS round-trip, no lgkm serialization between softmax and PV.
template <bool PRE>
__global__ __launch_bounds__(256, 4) void fattn_kernel(
    const float* __restrict__ Q, const unsigned short* __restrict__ Kbf,
    const unsigned short* __restrict__ Vt, const float* __restrict__ Kf,
    const float* __restrict__ Vf, float* __restrict__ Out)
{
    const int tid  = threadIdx.x;
    const int wave = tid >> 6;
    const int lane = tid & 63;
    const int ln   = lane & 15;
    const int quad = lane >> 4;
    const int qtile = gridDim.x - 1 - blockIdx.x;  // longest blocks first
    const int h = blockIdx.y;
    const int b = blockIdx.z;
    const int q0 = qtile * 64;
    const int qw = q0 + wave * 16;       // this wave's 16 q-rows
    const int p7 = ln & 7;
    const int qrow = qw + ln;            // this lane's q-row (S^T col = ln)

    __shared__ __align__(16) unsigned short ldsK[64 * 64];  // [key][e] swz
    __shared__ __align__(16) unsigned short ldsV[64 * 64];  // [e][key'] swz

    // Q fragments (B-operand for S^T; n=ln, k=c*32+quad*8+j), pre-scaled
    FragU qf[2];
    {
        const float* qp = Q + (((size_t)b * L_ + (qw + ln)) * H_ + h) * E_;
        for (int c = 0; c < 2; ++c) {
            const int e0 = c * 32 + quad * 8;
            f32x4 lo = *(const f32x4*)(qp + e0);
            f32x4 hi = *(const f32x4*)(qp + e0 + 4);
            ushort8 u;
            u[0]=f2bf(lo[0]*SCALE2); u[1]=f2bf(lo[1]*SCALE2);
            u[2]=f2bf(lo[2]*SCALE2); u[3]=f2bf(lo[3]*SCALE2);
            u[4]=f2bf(hi[0]*SCALE2); u[5]=f2bf(hi[1]*SCALE2);
            u[6]=f2bf(hi[2]*SCALE2); u[7]=f2bf(hi[3]*SCALE2);
            qf[c].u = u;
        }
    }

    f32x4 o[4];
    for (int et = 0; et < 4; ++et) o[et] = f32x4{0.f, 0.f, 0.f, 0.f};
    float lsum = 0.f;                    // per-lane row-sum for qrow

    const unsigned short* kbh = Kbf + (size_t)(b * H_ + h) * S_ * E_;
    const unsigned short* vbh = Vt  + (size_t)(b * H_ + h) * E_ * S_;
    const float* kf32 = Kf + (((size_t)b * S_) * H_ + h) * E_;
    const float* vf32 = Vf + (((size_t)b * S_) * H_ + h) * E_;

    const int ntiles = qtile + 1;        // keys 0 .. q0+63
    for (int kt = 0; kt < ntiles; ++kt) {
        const int k0 = kt * 64;
        __syncthreads();                 // prior tile's LDS reads complete

        if constexpr (PRE) {
            const unsigned short* ktb = kbh + (size_t)k0 * E_;
            const unsigned short* vtb = vbh + k0;
            for (int i = 0; i < 2; ++i) {          // K tile: 8KB linear DMA
                const int slot0 = wave * 128 + i * 64;
                gload_lds16(ktb + (size_t)(slot0 + lane) * 8, &ldsK[slot0 * 8]);
            }
            for (int i = 0; i < 2; ++i) {          // V tile: 64 rows x 128B DMA
                const int slot0 = wave * 128 + i * 64;
                const int slot  = slot0 + lane;
                const int e = slot >> 3, lc = slot & 7;
                gload_lds16(vtb + (size_t)e * S_ + lc * 8, &ldsV[slot0 * 8]);
            }
        } else {
            for (int i = 0; i < 2; ++i) {          // fp32 fallback staging
                const int c = tid + i * 256;
                const int key = c >> 3, j = c & 7, jp = j ^ (key & 7);
                const float* src = kf32 + (size_t)(k0 + key) * (H_ * E_) + jp * 8;
                f32x4 a = *(const f32x4*)src, d = *(const f32x4*)(src + 4);
                ushort8 u;
                u[0]=f2bf(a[0]); u[1]=f2bf(a[1]); u[2]=f2bf(a[2]); u[3]=f2bf(a[3]);
                u[4]=f2bf(d[0]); u[5]=f2bf(d[1]); u[6]=f2bf(d[2]); u[7]=f2bf(d[3]);
                *(ushort8*)&ldsK[key * 64 + j * 8] = u;
            }
            for (int i = 0; i < 2; ++i) {          // V with permuted-k layout
                const int c = tid + i * 256;
                const int e = c >> 3, cc = c & 7;
                const int q = cc >> 1, half = cc & 1;
                ushort8 u;
                for (int j = 0; j < 8; ++j) {
                    const int d = j >> 2, r = j & 3;
                    const int key = (2 * half + d) * 16 + q * 4 + r;
                    u[j] = f2bf(vf32[(size_t)(k0 + key) * (H_ * E_) + e]);
                }
                *(ushort8*)&ldsV[e * 64 + (cc ^ (e & 7)) * 8] = u;
            }
        }
        __syncthreads();                 // vmcnt drained: tile resident

        // S^T = K.Q^T : A = K-frag (m=key), B = Q-frag (n=qrow).
        // sfr[n]: lane holds (qrow=ln, key = k0 + n*16 + quad*4 + r).
        f32x4 sfr[4];
        for (int n = 0; n < 4; ++n) {
            FragU kf0, kf1;
            kf0.u = *(const ushort8*)&ldsK[(n*16+ln)*64 + ((quad    ) ^ p7) * 8];
            kf1.u = *(const ushort8*)&ldsK[(n*16+ln)*64 + ((4 + quad) ^ p7) * 8];
            f32x4 acc = f32x4{0.f, 0.f, 0.f, 0.f};
            acc = __builtin_amdgcn_mfma_f32_16x16x32_bf16(kf0.b, qf[0].b, acc, 0, 0, 0);
            acc = __builtin_amdgcn_mfma_f32_16x16x32_bf16(kf1.b, qf[1].b, acc, 0, 0, 0);
            sfr[n] = acc;
        }

        // max-free softmax, P packed in-register (truncation to bf16).
        // Mask only on the diagonal tile (wave-uniform branch).
        const bool need_mask = (kt == qtile);
        unsigned int pk[4][2];
        for (int n = 0; n < 4; ++n) {
            float p[4];
            for (int r = 0; r < 4; ++r) {
                float v = __builtin_exp2f(sfr[n][r]);
                if (need_mask) {
                    const int key = k0 + n * 16 + quad * 4 + r;
                    v = (key <= qrow) ? v : 0.f;
                }
                lsum += v;
                p[r] = v;
            }
            pk[n][0] = pack_bf(p[1], p[0]);
            pk[n][1] = pack_bf(p[3], p[2]);
        }
        FragU pf0, pf1;   // A-frags under permuted k: {n_lo r0-3, n_hi r0-3}
        pf0.d[0] = pk[0][0]; pf0.d[1] = pk[0][1];
        pf0.d[2] = pk[1][0]; pf0.d[3] = pk[1][1];
        pf1.d[0] = pk[2][0]; pf1.d[1] = pk[2][1];
        pf1.d[2] = pk[3][0]; pf1.d[3] = pk[3][1];

        // O += P.V (V B-frags use the same permuted-k order via Vt layout)
        for (int et = 0; et < 4; ++et) {
            FragU vf0, vf1;
            vf0.u = *(const ushort8*)&ldsV[(et*16+ln)*64 + ((2*quad    ) ^ p7) * 8];
            vf1.u = *(const ushort8*)&ldsV[(et*16+ln)*64 + ((2*quad + 1) ^ p7) * 8];
            o[et] = __builtin_amdgcn_mfma_f32_16x16x32_bf16(pf0.b, vf0.b, o[et], 0, 0, 0);
            o[et] = __builtin_amdgcn_mfma_f32_16x16x32_bf16(pf1.b, vf1.b, o[et], 0, 0, 0);
        }
    }

    // l: reduce across the 4 quads (lanes ln, ln+16, ln+32, ln+48)
    lsum += __shfl_xor(lsum, 16);
    lsum += __shfl_xor(lsum, 32);
    const float inv = 1.f / lsum;        // for qrow = qw + ln

    // Epilogue: O C-layout row=quad*4+r, col=et*16+ln; fetch 1/l via shuffle
    for (int r = 0; r < 4; ++r) {
        const int row = quad * 4 + r;
        const float invr = __shfl(inv, row);   // lane `row` has l for qw+row
        float* op = Out + (((size_t)b * L_ + (qw + row)) * H_ + h) * E_;
        for (int et = 0; et < 4; ++et)
            op[et * 16 + ln] = o[et][r] * invr;
    }
}

extern "C" void kernel_launch(void* const* d_in, const int* in_sizes, int n_in,
                              void* d_out, int out_size, void* d_ws, size_t ws_size,
                              hipStream_t stream) {
    const float* Q = (const float*)d_in[0];
    const float* K = (const float*)d_in[1];
    const float* V = (const float*)d_in[2];
    // d_in[3] (causal mask) applied analytically in-kernel.
    float* Out = (float*)d_out;

    const size_t plane = (size_t)B_ * H_ * S_ * E_;
    unsigned short* Kbf = (unsigned short*)d_ws;
    unsigned short* Vt  = Kbf + plane;

    dim3 grid(L_ / 64, H_, B_);
    if (ws_size >= plane * 2 * sizeof(unsigned short)) {
        conv_k<<<(int)(plane / 8 / 256), 256, 0, stream>>>(K, Kbf);
        conv_v<<<B_ * H_ * (S_ / 64), 256, 0, stream>>>(V, Vt);
        fattn_kernel<true><<<grid, dim3(256), 0, stream>>>(Q, Kbf, Vt, K, V, Out);
    } else {
        fattn_kernel<false><<<grid, dim3(256), 0, stream>>>(Q, Kbf, Vt, K, V, Out);
    }
}